// Round 4
// baseline (76.882 us; speedup 1.0000x reference)
//
#include <hip/hip_runtime.h>
#include <math.h>

// ContrastiveCenterLoss — algebraically collapsed.
//
// hn[b] = normalize(pool8(hidden[b])), cn[c] = normalize(pool8(center[c])),
// cbar = mean_c cn[c], S = sum_c outer(cn[c]-cbar), u = hn[b]-cbar.
// XY[b] = {100 copies of hn[b]} ∪ {cn[c]} (N=200 rows); mean = (hn+cbar)/2;
// X-part diffs = u/2 (×100) -> 25 uu^T; Y-part = d_c - u/2, Σd_c = 0 -> S + 25 uu^T.
//   bcov[b] = (S + 50 u u^T) / 199
//   pinv(bcov[b]) = 199 (Sinv - 50 (Sinv u)(u^T Sinv)/(1 + 50 u^T Sinv u))   [Sherman-Morrison]
//   m_dis[b,c] = 199 ( v^T Sinv v - coef (v·w)^2 ),  v = hn-cn[c], w = Sinv u,
//                coef = 50/(1+50 u·w)
//   loss_b = dis[b,y_b] - (Σ_c dis - dis[b,y_b])/99 ;  out = mean_b loss_b
//
// Correctness-first structure: every cross-lane LDS dependency is bracketed by
// __syncthreads() (round-1 failure was a barrier-free intra-wave Gauss-Jordan —
// compiler legally caches LDS in registers without a fence). No atomics, no
// counter-based finalize: per-block partials + tiny second kernel. Deterministic.

#define DIMH 512
#define NC   100
#define PG   8
#define GS   64     // elements per pooled group
#define RPB  4      // batch rows per block (= waves per block)

__global__ __launch_bounds__(256) void ccl_main_kernel(
    const float* __restrict__ hidden,   // [B][DIMH]
    const float* __restrict__ fc,       // [NC][DIMH]
    const int*   __restrict__ y,        // [B]
    double* __restrict__ partials,      // [gridDim.x]
    int B)
{
    __shared__ float  cn[NC][PG];
    __shared__ float  cbarS[PG];
    __shared__ float  SinvS[64];
    __shared__ double Am[8][16];        // augmented [S | I]
    __shared__ double wpart[RPB];

    const int tid  = threadIdx.x;
    const int lane = tid & 63;
    const int wave = tid >> 6;
    const int b    = blockIdx.x * RPB + wave;

    // ---- early-issue per-row loads; latency hides under center stats ----
    float4 h0 = make_float4(0.f, 0.f, 0.f, 0.f);
    float4 h1 = make_float4(0.f, 0.f, 0.f, 0.f);
    int yt = -1;
    if (b < B) {
        const float4* hrow = reinterpret_cast<const float4*>(hidden + (size_t)b * DIMH) + lane * 2;
        h0 = hrow[0];
        h1 = hrow[1];
        yt = y[b];
    }

    // ---- pool centers: wave w handles rows c = w, w+RPB, ... ----
    for (int c = wave; c < NC; c += RPB) {
        const float4* row = reinterpret_cast<const float4*>(fc + (size_t)c * DIMH) + lane * 2;
        float4 a = row[0];
        float4 d = row[1];
        float s = a.x + a.y + a.z + a.w + d.x + d.y + d.z + d.w;
        s += __shfl_xor(s, 1);
        s += __shfl_xor(s, 2);
        s += __shfl_xor(s, 4);
        if ((lane & 7) == 0) cn[c][lane >> 3] = s * (1.0f / GS);
    }
    __syncthreads();

    // ---- normalize each center row ----
    if (tid < NC) {
        float v[PG];
        float n2 = 0.0f;
#pragma unroll
        for (int g = 0; g < PG; ++g) { v[g] = cn[tid][g]; n2 += v[g] * v[g]; }
        float inv = 1.0f / (sqrtf(n2) + 1e-6f);
#pragma unroll
        for (int g = 0; g < PG; ++g) cn[tid][g] = v[g] * inv;
    }
    __syncthreads();

    // ---- cbar ----
    if (tid < PG) {
        float s = 0.0f;
        for (int c = 0; c < NC; ++c) s += cn[c][tid];
        cbarS[tid] = s * (1.0f / NC);
    }
    __syncthreads();

    // ---- S (f64) ----
    const int i = tid >> 3, j = tid & 7;
    if (tid < 64) {
        float ci = cbarS[i], cj = cbarS[j];
        double s = 0.0;
        for (int c = 0; c < NC; ++c)
            s += (double)(cn[c][i] - ci) * (double)(cn[c][j] - cj);
        Am[i][j]     = s;
        Am[i][j + 8] = (i == j) ? 1.0 : 0.0;
    }
    __syncthreads();

    // ---- Gauss-Jordan inverse (SPD, diagonal pivots), block barriers ----
#pragma unroll 1
    for (int k = 0; k < 8; ++k) {
        double piv = (tid < 64) ? Am[k][k] : 1.0;
        __syncthreads();
        if (tid < 64 && i == k) { Am[k][j] /= piv; Am[k][j + 8] /= piv; }
        __syncthreads();
        double f    = (tid < 64) ? Am[i][k]     : 0.0;
        double akj  = (tid < 64) ? Am[k][j]     : 0.0;
        double akj8 = (tid < 64) ? Am[k][j + 8] : 0.0;
        __syncthreads();
        if (tid < 64 && i != k) { Am[i][j] -= f * akj; Am[i][j + 8] -= f * akj8; }
        __syncthreads();
    }
    if (tid < 64) SinvS[tid] = (float)Am[i][j + 8];
    __syncthreads();

    // ---- per-row loss (wave-local; registers + shfl only) ----
    double loss_b = 0.0;
    if (b < B) {
        float s = h0.x + h0.y + h0.z + h0.w + h1.x + h1.y + h1.z + h1.w;
        s += __shfl_xor(s, 1);
        s += __shfl_xor(s, 2);
        s += __shfl_xor(s, 4);

        float hn[PG];
        float n2 = 0.0f;
#pragma unroll
        for (int g = 0; g < PG; ++g) {
            hn[g] = __shfl(s, g << 3) * (1.0f / GS);
            n2 += hn[g] * hn[g];
        }
        float inv = 1.0f / (sqrtf(n2) + 1e-6f);
#pragma unroll
        for (int g = 0; g < PG; ++g) hn[g] *= inv;

        float u[PG], w[PG];
#pragma unroll
        for (int g = 0; g < PG; ++g) u[g] = hn[g] - cbarS[g];
        float uw = 0.0f;
#pragma unroll
        for (int ii = 0; ii < PG; ++ii) {
            float t = 0.0f;
#pragma unroll
            for (int jj = 0; jj < PG; ++jj) t += SinvS[ii * 8 + jj] * u[jj];
            w[ii] = t;
            uw += u[ii] * t;
        }
        const float coef = 50.0f / (1.0f + 50.0f * uw);

        float sumd = 0.0f, disy = 0.0f;
        for (int c = lane; c < NC; c += 64) {
            float v[PG];
#pragma unroll
            for (int g = 0; g < PG; ++g) v[g] = hn[g] - cn[c][g];
            float q1 = 0.0f, q2 = 0.0f;
#pragma unroll
            for (int ii = 0; ii < PG; ++ii) {
                float t = 0.0f;
#pragma unroll
                for (int jj = 0; jj < PG; ++jj) t += SinvS[ii * 8 + jj] * v[jj];
                q1 += v[ii] * t;
                q2 += v[ii] * w[ii];
            }
            float m = 199.0f * (q1 - coef * q2 * q2);
            float d = sqrtf(fmaxf(m, 0.0f));
            sumd += d;
            if (c == yt) disy = d;
        }
#pragma unroll
        for (int off = 1; off < 64; off <<= 1) {
            sumd += __shfl_xor(sumd, off);
            disy += __shfl_xor(disy, off);
        }
        loss_b = (double)disy - (double)(sumd - disy) * (1.0 / 99.0);
    }

    if (lane == 0) wpart[wave] = loss_b;
    __syncthreads();

    if (tid == 0)
        partials[blockIdx.x] = wpart[0] + wpart[1] + wpart[2] + wpart[3];
}

__global__ __launch_bounds__(256) void ccl_finalize_kernel(
    const double* __restrict__ partials, float* __restrict__ out, int n, int B)
{
    __shared__ double sh[4];
    const int tid = threadIdx.x, lane = tid & 63, wave = tid >> 6;
    double v = (tid < n) ? partials[tid] : 0.0;
#pragma unroll
    for (int off = 1; off < 64; off <<= 1) v += __shfl_xor(v, off);
    if (lane == 0) sh[wave] = v;
    __syncthreads();
    if (tid == 0) out[0] = (float)((sh[0] + sh[1] + sh[2] + sh[3]) / (double)B);
}

extern "C" void kernel_launch(void* const* d_in, const int* in_sizes, int n_in,
                              void* d_out, int out_size, void* d_ws, size_t ws_size,
                              hipStream_t stream)
{
    const float* hidden = (const float*)d_in[0];
    const float* fc     = (const float*)d_in[1];
    const int*   y      = (const int*)d_in[2];
    float*       out    = (float*)d_out;

    const int B = in_sizes[0] / DIMH;           // 1024
    const int nblocks = (B + RPB - 1) / RPB;    // 256

    double* partials = (double*)d_ws;           // nblocks doubles

    ccl_main_kernel<<<nblocks, 256, 0, stream>>>(hidden, fc, y, partials, B);
    ccl_finalize_kernel<<<1, 256, 0, stream>>>(partials, out, nblocks, B);
}

// Round 5
// 70.542 us; speedup vs baseline: 1.0899x; 1.0899x over previous
//
#include <hip/hip_runtime.h>
#include <math.h>

// ContrastiveCenterLoss — algebraically collapsed.
//
// hn[b] = normalize(pool8(hidden[b])), cn[c] = normalize(pool8(center[c])),
// cbar = mean_c cn[c], S = sum_c outer(cn[c]-cbar), u = hn[b]-cbar.
//   bcov[b] = (S + 50 u u^T) / 199
//   pinv(bcov[b]) = 199 (Sinv - 50 (Sinv u)(u^T Sinv)/(1 + 50 u^T Sinv u))  [Sherman-Morrison]
//   m_dis[b,c] = 199 ( v^T Sinv v - coef (v·w)^2 ),  v = hn-cn[c], w = Sinv u,
//                coef = 50/(1+50 u·w)
//   loss_b = dis[b,y_b] - (Σ_c dis - dis[b,y_b])/99 ;  out = mean_b loss_b
//
// Sync discipline (round-1 lesson): cross-lane data flow through LDS is always
// bracketed by __syncthreads(); cross-lane data flow through __shfl needs no
// barrier (explicit register traffic). The 8x8 inverse is now a wave-0
// register/shfl Jordan elimination — 0 barriers, 0 LDS, f32 (reference is f32).
// Barriers: 38 -> 5.

#define DIMH 512
#define NC   100
#define PG   8
#define GS   64     // elements per pooled group
#define RPB  4      // batch rows per block (= waves per block)

__global__ __launch_bounds__(256) void ccl_main_kernel(
    const float* __restrict__ hidden,   // [B][DIMH]
    const float* __restrict__ fc,       // [NC][DIMH]
    const int*   __restrict__ y,        // [B]
    double* __restrict__ partials,      // [gridDim.x]
    int B)
{
    __shared__ float  cn[NC][PG];
    __shared__ float  cbarS[PG];
    __shared__ float  SinvS[64];
    __shared__ float  Spart[RPB][64];
    __shared__ double wpart[RPB];

    const int tid  = threadIdx.x;
    const int lane = tid & 63;
    const int wave = tid >> 6;
    const int b    = blockIdx.x * RPB + wave;

    // ---- early-issue per-row loads; latency hides under center stats ----
    float4 h0 = make_float4(0.f, 0.f, 0.f, 0.f);
    float4 h1 = make_float4(0.f, 0.f, 0.f, 0.f);
    int yt = -1;
    if (b < B) {
        const float4* hrow = reinterpret_cast<const float4*>(hidden + (size_t)b * DIMH) + lane * 2;
        h0 = hrow[0];
        h1 = hrow[1];
        yt = y[b];
    }

    // ---- pool centers: wave w handles rows c = w, w+RPB, ... (coalesced) ----
    for (int c = wave; c < NC; c += RPB) {
        const float4* row = reinterpret_cast<const float4*>(fc + (size_t)c * DIMH) + lane * 2;
        float4 a = row[0];
        float4 d = row[1];
        float s = a.x + a.y + a.z + a.w + d.x + d.y + d.z + d.w;
        s += __shfl_xor(s, 1);
        s += __shfl_xor(s, 2);
        s += __shfl_xor(s, 4);
        if ((lane & 7) == 0) cn[c][lane >> 3] = s * (1.0f / GS);
    }
    __syncthreads();                                   // barrier 1

    // ---- normalize each center row ----
    if (tid < NC) {
        float v[PG];
        float n2 = 0.0f;
#pragma unroll
        for (int g = 0; g < PG; ++g) { v[g] = cn[tid][g]; n2 += v[g] * v[g]; }
        float inv = 1.0f / (sqrtf(n2) + 1e-6f);
#pragma unroll
        for (int g = 0; g < PG; ++g) cn[tid][g] = v[g] * inv;
    }
    __syncthreads();                                   // barrier 2

    // ---- concurrent: wave 1 computes cbar (shfl-reduce); all waves S-partials ----
    if (wave == 1) {
        const int g = lane & 7, t = lane >> 3;         // t in 0..7
        float s = 0.0f;
        for (int c = t; c < NC; c += 8) s += cn[c][g];
        s += __shfl_xor(s, 8);
        s += __shfl_xor(s, 16);
        s += __shfl_xor(s, 32);
        if (t == 0) cbarS[g] = s * (1.0f / NC);
    }
    {
        const int i = lane >> 3, j = lane & 7;
        const int c0 = wave * (NC / RPB);
        float s = 0.0f;
        for (int c = c0; c < c0 + NC / RPB; ++c) s += cn[c][i] * cn[c][j];
        Spart[wave][lane] = s;
    }
    __syncthreads();                                   // barrier 3

    // ---- wave 0: assemble S, invert 8x8 via register/shfl Jordan (f32) ----
    if (wave == 0) {
        const int i = lane >> 3, j = lane & 7;
        float a = Spart[0][lane] + Spart[1][lane] + Spart[2][lane] + Spart[3][lane]
                - (float)NC * cbarS[i] * cbarS[j];     // S = Σ cncnᵀ − 100 cbarcbarᵀ
        float binv = (i == j) ? 1.0f : 0.0f;
#pragma unroll
        for (int k = 0; k < 8; ++k) {
            // all shfls read pre-update values (program order before writes)
            float akk = __shfl(a,    k * 8 + k);
            float aik = __shfl(a,    i * 8 + k);
            float akj = __shfl(a,    k * 8 + j);
            float bkj = __shfl(binv, k * 8 + j);
            float r = 1.0f / akk;
            if (i == k) { a *= r;            binv *= r; }
            else        { float f = aik * r; a -= f * akj; binv -= f * bkj; }
        }
        SinvS[lane] = binv;
    }
    __syncthreads();                                   // barrier 4

    // ---- per-row loss (wave-local; registers + shfl only) ----
    double loss_b = 0.0;
    if (b < B) {
        float s = h0.x + h0.y + h0.z + h0.w + h1.x + h1.y + h1.z + h1.w;
        s += __shfl_xor(s, 1);
        s += __shfl_xor(s, 2);
        s += __shfl_xor(s, 4);

        float hn[PG];
        float n2 = 0.0f;
#pragma unroll
        for (int g = 0; g < PG; ++g) {
            hn[g] = __shfl(s, g << 3) * (1.0f / GS);
            n2 += hn[g] * hn[g];
        }
        float inv = 1.0f / (sqrtf(n2) + 1e-6f);
#pragma unroll
        for (int g = 0; g < PG; ++g) hn[g] *= inv;

        float u[PG], w[PG];
#pragma unroll
        for (int g = 0; g < PG; ++g) u[g] = hn[g] - cbarS[g];
        float uw = 0.0f;
#pragma unroll
        for (int ii = 0; ii < PG; ++ii) {
            float t = 0.0f;
#pragma unroll
            for (int jj = 0; jj < PG; ++jj) t += SinvS[ii * 8 + jj] * u[jj];
            w[ii] = t;
            uw += u[ii] * t;
        }
        const float coef = 50.0f / (1.0f + 50.0f * uw);

        float sumd = 0.0f, disy = 0.0f;
        for (int c = lane; c < NC; c += 64) {
            float v[PG];
#pragma unroll
            for (int g = 0; g < PG; ++g) v[g] = hn[g] - cn[c][g];
            float q1 = 0.0f, q2 = 0.0f;
#pragma unroll
            for (int ii = 0; ii < PG; ++ii) {
                float t = 0.0f;
#pragma unroll
                for (int jj = 0; jj < PG; ++jj) t += SinvS[ii * 8 + jj] * v[jj];
                q1 += v[ii] * t;
                q2 += v[ii] * w[ii];
            }
            float m = 199.0f * (q1 - coef * q2 * q2);
            float d = sqrtf(fmaxf(m, 0.0f));
            sumd += d;
            if (c == yt) disy = d;
        }
#pragma unroll
        for (int off = 1; off < 64; off <<= 1) {
            sumd += __shfl_xor(sumd, off);
            disy += __shfl_xor(disy, off);
        }
        loss_b = (double)disy - (double)(sumd - disy) * (1.0 / 99.0);
    }

    if (lane == 0) wpart[wave] = loss_b;
    __syncthreads();                                   // barrier 5

    if (tid == 0)
        partials[blockIdx.x] = wpart[0] + wpart[1] + wpart[2] + wpart[3];
}

__global__ __launch_bounds__(256) void ccl_finalize_kernel(
    const double* __restrict__ partials, float* __restrict__ out, int n, int B)
{
    __shared__ double sh[4];
    const int tid = threadIdx.x, lane = tid & 63, wave = tid >> 6;
    double v = (tid < n) ? partials[tid] : 0.0;
#pragma unroll
    for (int off = 1; off < 64; off <<= 1) v += __shfl_xor(v, off);
    if (lane == 0) sh[wave] = v;
    __syncthreads();
    if (tid == 0) out[0] = (float)((sh[0] + sh[1] + sh[2] + sh[3]) / (double)B);
}

extern "C" void kernel_launch(void* const* d_in, const int* in_sizes, int n_in,
                              void* d_out, int out_size, void* d_ws, size_t ws_size,
                              hipStream_t stream)
{
    const float* hidden = (const float*)d_in[0];
    const float* fc     = (const float*)d_in[1];
    const int*   y      = (const int*)d_in[2];
    float*       out    = (float*)d_out;

    const int B = in_sizes[0] / DIMH;           // 1024
    const int nblocks = (B + RPB - 1) / RPB;    // 256

    double* partials = (double*)d_ws;           // nblocks doubles

    ccl_main_kernel<<<nblocks, 256, 0, stream>>>(hidden, fc, y, partials, B);
    ccl_finalize_kernel<<<1, 256, 0, stream>>>(partials, out, nblocks, B);
}